// Round 2
// baseline (62.277 us; speedup 1.0000x reference)
//
#include <hip/hip_runtime.h>

#define HW_   (512*512)         // 262144 pixels per image
#define NC    16
#define NB    8
#define NPIX  (NB*HW_)          // 2097152
#define GPB2  (HW_/2)           // 131072 float2-groups per image (2^17)
#define NGRP2 (NPIX/2)          // 1048576 total float2-groups
#define NBLK  1024
#define NTHR  256
#define NBUK  64                // bucket rows for partials

// ws layout (floats): [NBUK][48] partial stats; ws[3072] = block counter (int)
// stat s: 0..15 = p_sum[c], 16..31 = intersection[c], 32..47 = t_sum[c]

__device__ __forceinline__ float wred(float v) {
    v += __shfl_xor(v, 32, 64);
    v += __shfl_xor(v, 16, 64);
    v += __shfl_xor(v,  8, 64);
    v += __shfl_xor(v,  4, 64);
    v += __shfl_xor(v,  2, 64);
    v += __shfl_xor(v,  1, 64);
    return v;
}

__global__ __launch_bounds__(NTHR, 4) void dice_main(
        const float* __restrict__ logits,
        const int*   __restrict__ targets,
        float*       __restrict__ ws,
        float*       __restrict__ out) {
    __shared__ float lds_inter[NC];
    __shared__ float red[4][2*NC];
    __shared__ float fin[48];
    __shared__ int   isLast;

    const int tid = threadIdx.x;
    if (tid < NC) lds_inter[tid] = 0.0f;
    __syncthreads();

    float psum[NC];
    #pragma unroll
    for (int c = 0; c < NC; ++c) psum[c] = 0.0f;
    unsigned tlo = 0u, thi = 0u;   // packed nibble counts, classes 0-7 / 8-15

    const float2* __restrict__ lf2 = reinterpret_cast<const float2*>(logits);
    const int2*   __restrict__ tg2 = reinterpret_cast<const int2*>(targets);

    int g = blockIdx.x * NTHR + tid;
    #pragma unroll 1
    for (int k = 0; k < 4; ++k, g += NBLK * NTHR) {
        const int b  = g >> 17;            // g / GPB2
        const int s2 = g & (GPB2 - 1);     // g % GPB2
        const float2* lp = lf2 + (size_t)b * (NC * GPB2) + s2;
        const int2 t = tg2[(size_t)b * GPB2 + s2];

        float ex[NC], ey[NC];
        float sx = 0.0f, sy = 0.0f;
        #pragma unroll
        for (int c = 0; c < NC; ++c) {
            float2 l = lp[(size_t)c * GPB2];
            ex[c] = __expf(l.x); ey[c] = __expf(l.y);
            sx += ex[c]; sy += ey[c];
        }
        const float ix = __builtin_amdgcn_rcpf(sx);
        const float iy = __builtin_amdgcn_rcpf(sy);

        #pragma unroll
        for (int c = 0; c < NC; ++c) {
            psum[c] = fmaf(ex[c], ix, psum[c]);
            psum[c] = fmaf(ey[c], iy, psum[c]);
        }

        // target-class prob: re-load the one logit (L1/L2 hit, same line this
        // wave just fetched), re-exp, normalize, LDS-atomic into inter[t].
        const float* lpx = logits + (size_t)b * (NC * HW_) + 2 * s2;
        if ((unsigned)t.x < (unsigned)NC) {
            const float pt = __expf(lpx[(size_t)t.x * HW_]) * ix;
            atomicAdd(&lds_inter[t.x], pt);
            const unsigned inc = 1u << (4 * (t.x & 7));
            if (t.x < 8) tlo += inc; else thi += inc;
        }
        if ((unsigned)t.y < (unsigned)NC) {
            const float pt = __expf(lpx[(size_t)t.y * HW_ + 1]) * iy;
            atomicAdd(&lds_inter[t.y], pt);
            const unsigned inc = 1u << (4 * (t.y & 7));
            if (t.y < 8) tlo += inc; else thi += inc;
        }
    }

    // ---- block reduction ----
    const int lane = tid & 63, wv = tid >> 6;
    #pragma unroll
    for (int c = 0; c < NC; ++c) {
        float r = wred(psum[c]);
        if (lane == 0) red[wv][c] = r;
    }
    #pragma unroll
    for (int c = 0; c < NC; ++c) {
        float tc = (c < 8) ? (float)((tlo >> (4 * c)) & 15u)
                           : (float)((thi >> (4 * (c - 8))) & 15u);
        float r = wred(tc);
        if (lane == 0) red[wv][NC + c] = r;
    }
    __syncthreads();

    if (tid < 48) {
        float v;
        if (tid < 16)      v = red[0][tid] + red[1][tid] + red[2][tid] + red[3][tid];
        else if (tid < 32) v = lds_inter[tid - 16];
        else { const int c = tid - 32;
               v = red[0][NC+c] + red[1][NC+c] + red[2][NC+c] + red[3][NC+c]; }
        atomicAdd(&ws[(blockIdx.x & (NBUK - 1)) * 48 + tid], v);
        __threadfence();
    }
    __syncthreads();

    // ---- last-block finalize ----
    if (tid == 0) {
        int old = atomicAdd((int*)(ws + NBUK * 48), 1);
        isLast = (old == (int)gridDim.x - 1);
    }
    __syncthreads();
    if (!isLast) return;

    __threadfence();
    if (tid < 48) {
        float s = 0.0f;
        #pragma unroll 8
        for (int b2 = 0; b2 < NBUK; ++b2)
            s += atomicAdd(&ws[b2 * 48 + tid], 0.0f);   // device-scope read
        fin[tid] = s;
    }
    __syncthreads();
    if (tid == 0) {
        float acc = 0.0f;
        #pragma unroll
        for (int c = 0; c < NC; ++c) {
            const float dice = (2.0f * fin[16 + c] + 1.0f) / (fin[c] + fin[32 + c] + 1.0f);
            acc += 1.0f - dice;
        }
        out[0] = acc * (1.0f / 16.0f);
    }
}

extern "C" void kernel_launch(void* const* d_in, const int* in_sizes, int n_in,
                              void* d_out, int out_size, void* d_ws, size_t ws_size,
                              hipStream_t stream) {
    const float* logits  = (const float*)d_in[0];
    const int*   targets = (const int*)d_in[1];
    float* ws  = (float*)d_ws;
    float* out = (float*)d_out;

    hipMemsetAsync(ws, 0, 16384, stream);  // buckets + counter
    dice_main<<<NBLK, NTHR, 0, stream>>>(logits, targets, ws, out);
}